// Round 19
// baseline (353.096 us; speedup 1.0000x reference)
//
#include <hip/hip_runtime.h>
#include <cstdint>
#include <cstddef>

#define P_DIM 8
#define U_DIM 256
#define V_DIM 256
#define F_DIM 12544   // 256*49

typedef __attribute__((ext_vector_type(8))) short short8;
typedef __attribute__((ext_vector_type(8))) _Float16 half8;
typedef __attribute__((ext_vector_type(4))) float f32x4;

#define MFMA16B(a, b, c) __builtin_amdgcn_mfma_f32_16x16x32_bf16((a), (b), (c), 0, 0, 0)
#define MFMA16H(a, b, c) __builtin_amdgcn_mfma_f32_16x16x32_f16((a), (b), (c), 0, 0, 0)

// async global->LDS, 16B per lane; LDS dest must be the wave-uniform base
#define GLOAD16(gsrc, ldsbase)                                                \
  __builtin_amdgcn_global_load_lds(                                           \
      (const __attribute__((address_space(1))) void*)(gsrc),                  \
      (__attribute__((address_space(3))) void*)(ldsbase), 16, 0, 0)

__device__ __forceinline__ unsigned short f2bf(float x) {      // RNE
  unsigned u = __builtin_bit_cast(unsigned, x);
  u += 0x7FFFu + ((u >> 16) & 1u);
  return (unsigned short)(u >> 16);
}
__device__ __forceinline__ unsigned short f2h(float x) {       // RNE fp16
  return __builtin_bit_cast(unsigned short, (_Float16)x);
}

// ---------------------------------------------------------------------------
// 1) prep_fv: reads fv ONCE; writes fvT bf16 [p][f][v], fvH fp16 [p][v][f],
//    fp32 vv partials.   (R15-identical)
// ---------------------------------------------------------------------------
__global__ __launch_bounds__(256) void prep_fv(const float* __restrict__ fv,
                                               unsigned short* __restrict__ fvT,
                                               unsigned short* __restrict__ fvH,
                                               float* __restrict__ vvpart) {
  __shared__ unsigned short tile[64][65];
  __shared__ float vvp[64];
  int f0 = blockIdx.x * 64, v0 = blockIdx.y * 64, p = blockIdx.z;
  const float* src = fv + (size_t)p * V_DIM * F_DIM;
  unsigned short* dstH = fvH + (size_t)p * V_DIM * F_DIM;
  int t = threadIdx.x;
  #pragma unroll
  for (int i = 0; i < 4; ++i) {
    int g = t + i * 256;                     // 0..1023
    int r = g >> 4;                          // v row 0..63
    int c4 = (g & 15) * 4;                   // f col
    float4 x = *(const float4*)(src + (size_t)(v0 + r) * F_DIM + f0 + c4);
    tile[r][c4 + 0] = f2bf(x.x);
    tile[r][c4 + 1] = f2bf(x.y);
    tile[r][c4 + 2] = f2bf(x.z);
    tile[r][c4 + 3] = f2bf(x.w);
    ushort4 h;
    h.x = f2h(x.x); h.y = f2h(x.y); h.z = f2h(x.z); h.w = f2h(x.w);
    *(ushort4*)(dstH + (size_t)(v0 + r) * F_DIM + f0 + c4) = h;
    float ps = x.x * x.x + x.y * x.y + x.z * x.z + x.w * x.w;
    ps += __shfl_xor(ps, 1); ps += __shfl_xor(ps, 2);
    ps += __shfl_xor(ps, 4); ps += __shfl_xor(ps, 8);
    if ((t & 15) == 0) vvp[r] = ps;
  }
  __syncthreads();
  if (t < 64)
    vvpart[((size_t)blockIdx.x * P_DIM + p) * V_DIM + v0 + t] = vvp[t];
  unsigned short* dst = fvT + (size_t)p * F_DIM * V_DIM;
  #pragma unroll
  for (int i = 0; i < 2; ++i) {
    int g = t + i * 256;                     // 0..511
    int f = g >> 3;                          // 0..63
    int v8 = (g & 7) * 8;
    short8 o;
    #pragma unroll
    for (int j = 0; j < 8; ++j) o[j] = (short)tile[v8 + j][f];
    *(short8*)(dst + (size_t)(f0 + f) * V_DIM + v0 + v8) = o;
  }
}

// ---------------------------------------------------------------------------
// 2) vv_reduce: 32 blocks, 4-way k-split per block
// ---------------------------------------------------------------------------
__global__ __launch_bounds__(256) void vv_reduce(const float* __restrict__ vvpart,
                                                 float* __restrict__ vv) {
  int p = blockIdx.x >> 2;
  int vb = (blockIdx.x & 3) * 64;
  int vl = threadIdx.x & 63;
  int v = vb + vl;
  int js = threadIdx.x >> 6;                 // 0..3
  float s = 0.f;
  for (int j = js; j < F_DIM / 64; j += 4)
    s += vvpart[((size_t)j * P_DIM + p) * V_DIM + v];
  __shared__ float red[4][64];
  red[js][vl] = s;
  __syncthreads();
  if (threadIdx.x < 64)
    vv[p * V_DIM + v] = red[0][vl] + red[1][vl] + red[2][vl] + red[3][vl];
}

// ---------------------------------------------------------------------------
// 3) copy_fu: feat_u -> out[0 : P*U*F] (fp32) AND fuH fp16 [p][u][f]
// ---------------------------------------------------------------------------
__global__ __launch_bounds__(256) void copy_fu(const float4* __restrict__ src,
                                               float4* __restrict__ dst,
                                               ushort4* __restrict__ fuH, int n4) {
  for (int i = blockIdx.x * 256 + threadIdx.x; i < n4; i += gridDim.x * 256) {
    float4 x = src[i];
    dst[i] = x;
    ushort4 h;
    h.x = f2h(x.x); h.y = f2h(x.y); h.z = f2h(x.z); h.w = f2h(x.w);
    fuH[i] = h;
  }
}

// ---------------------------------------------------------------------------
// 4) uv_gemm v13 (R15-identical T14 structure) + DIAGNOSTIC reps=4
//    (exact 1/4 rescale at store; rep-loop validated in R10).
// ---------------------------------------------------------------------------
__global__ __launch_bounds__(256, 2) void uv_gemm(const unsigned short* __restrict__ fuH,
                                                  const unsigned short* __restrict__ fvH,
                                                  float* __restrict__ part,
                                                  int splitk, int chunk,
                                                  int reps, float scale) {
  // bijective XCD chunk swizzle (m204)
  int nwg = gridDim.x;
  int q = nwg >> 3, r = nwg & 7;
  int xcd = blockIdx.x & 7, ofs = blockIdx.x >> 3;
  int wgid = (xcd < r ? xcd * (q + 1) : r * (q + 1) + (xcd - r) * q) + ofs;
  int nt = wgid & 1, mt = (wgid >> 1) & 1, p = (wgid >> 2) & 7, ks = wgid >> 5;

  const unsigned short* A = fuH + ((size_t)p * U_DIM + mt * 128) * F_DIM;
  const unsigned short* B = fvH + ((size_t)p * V_DIM + nt * 128) * F_DIM;
  int k0 = ks * chunk;
  int nkt = chunk >> 6;

  __shared__ short AS[2][128 * 64], BS[2][128 * 64];   // 64 KB (fp16, dbuf)

  int tid = threadIdx.x, lane = tid & 63, wid = tid >> 6;
  int wm = wid >> 1, wn = wid & 1;           // 2x2 waves, 64x64 each
  int rl = lane & 15;
  f32x4 acc[4][4] = {};
  short8 ra[4], rb[4];                       // staged tile regs (32 VGPR)

#define LOADR(kg)                                                             \
  do {                                                                        \
    _Pragma("unroll") for (int j = 0; j < 4; ++j) {                           \
      int g = tid + j * 256;                                                  \
      int row = g >> 3, c = g & 7;                                            \
      ra[j] = *(const short8*)(A + (size_t)row * F_DIM + (kg) + c * 8);       \
      rb[j] = *(const short8*)(B + (size_t)row * F_DIM + (kg) + c * 8);       \
    }                                                                         \
  } while (0)

#define WRITES(buf)                                                           \
  do {                                                                        \
    _Pragma("unroll") for (int j = 0; j < 4; ++j) {                           \
      int g = tid + j * 256;                                                  \
      int row = g >> 3, c = g & 7;                                            \
      int off = (row * 128 + c * 16) ^ ((row & 7) << 4);                      \
      *(short8*)((char*)AS[buf] + off) = ra[j];                               \
      *(short8*)((char*)BS[buf] + off) = rb[j];                               \
    }                                                                         \
  } while (0)

  for (int rep = 0; rep < reps; ++rep) {
    LOADR(k0);
    WRITES(0);
    __syncthreads();
    int cur = 0;
    for (int kt = 0; kt < nkt; ++kt) {
      bool more = (kt + 1 < nkt);
      if (more) LOADR(k0 + (kt + 1) * 64);   // issue EARLY (T14)
      const char* Ap = (const char*)AS[cur];
      const char* Bp = (const char*)BS[cur];
      #pragma unroll
      for (int kk = 0; kk < 2; ++kk) {
        int kbyte = kk * 64 + (lane >> 4) * 16;
        half8 ah[4], bh[4];
        #pragma unroll
        for (int m = 0; m < 4; ++m) {
          int row = wm * 64 + m * 16 + rl;
          int off = (row * 128 + kbyte) ^ ((row & 7) << 4);
          ah[m] = *(const half8*)(Ap + off);
        }
        #pragma unroll
        for (int n = 0; n < 4; ++n) {
          int row = wn * 64 + n * 16 + rl;
          int off = (row * 128 + kbyte) ^ ((row & 7) << 4);
          bh[n] = *(const half8*)(Bp + off);
        }
        #pragma unroll
        for (int m = 0; m < 4; ++m)
          #pragma unroll
          for (int n = 0; n < 4; ++n)
            acc[m][n] = MFMA16H(ah[m], bh[n], acc[m][n]);
      }
      if (more) WRITES(cur ^ 1);             // write LATE (vmcnt lands here)
      __syncthreads();
      cur ^= 1;
    }
  }
#undef LOADR
#undef WRITES
  float* dst = part + ((size_t)ks * P_DIM + p) * U_DIM * V_DIM;
  int rq = lane >> 4;
  #pragma unroll
  for (int m = 0; m < 4; ++m)
    #pragma unroll
    for (int n = 0; n < 4; ++n)
      #pragma unroll
      for (int i = 0; i < 4; ++i) {
        int u = mt * 128 + wm * 64 + m * 16 + rq * 4 + i;
        int v = nt * 128 + wn * 64 + n * 16 + rl;
        dst[(size_t)u * V_DIM + v] = acc[m][n][i] * scale;
      }
}

// ---------------------------------------------------------------------------
// 5) reduce partials + softmax over v -> bf16 score.  logit = 0.1*vv - 0.2*uv
// ---------------------------------------------------------------------------
__global__ __launch_bounds__(256) void reduce_softmax(const float* __restrict__ part,
                                                      const float* __restrict__ vv,
                                                      unsigned short* __restrict__ score,
                                                      int splitk) {
  int u = blockIdx.x & 255, p = blockIdx.x >> 8;
  int v = threadIdx.x;
  size_t base = ((size_t)p * U_DIM + u) * V_DIM + v;
  float s = 0.f;
  for (int k = 0; k < splitk; ++k)
    s += part[(size_t)k * (P_DIM * U_DIM * V_DIM) + base];
  float logit = 0.1f * vv[p * V_DIM + v] - 0.2f * s;
  float m = logit;
  #pragma unroll
  for (int off = 32; off >= 1; off >>= 1) m = fmaxf(m, __shfl_xor(m, off));
  __shared__ float red[4], red2[4];
  int lane = v & 63, wid = v >> 6;
  if (lane == 0) red[wid] = m;
  __syncthreads();
  m = fmaxf(fmaxf(red[0], red[1]), fmaxf(red[2], red[3]));
  float e = __expf(logit - m);
  float tsum = e;
  #pragma unroll
  for (int off = 32; off >= 1; off >>= 1) tsum += __shfl_xor(tsum, off);
  if (lane == 0) red2[wid] = tsum;
  __syncthreads();
  tsum = red2[0] + red2[1] + red2[2] + red2[3];
  score[base] = f2bf(e / tsum);
}

// ---------------------------------------------------------------------------
// 6) pv_gemm v6 (R15-identical structure) + DIAGNOSTIC reps=16
//    (exact 1/16 rescale; rep-loop validated in R12).
// ---------------------------------------------------------------------------
__global__ __launch_bounds__(256, 2) void pv_gemm(const unsigned short* __restrict__ score,
                                                  const unsigned short* __restrict__ fvT,
                                                  float* __restrict__ outneg,
                                                  int reps, float scale) {
  int my = blockIdx.x;                       // u half 0..1 (fastest)
  int bx = blockIdx.y;                       // f tile 0..195 (64 wide)
  int p = blockIdx.z;
  int n0 = bx * 64;
  const unsigned short* Sc = score + ((size_t)p * U_DIM + my * 128) * V_DIM;
  const unsigned short* Bt = fvT + ((size_t)p * F_DIM + n0) * V_DIM;
  __shared__ short Bs[64 * 256];             // 32 KB
  char* Bsp = (char*)Bs;
  int tid = threadIdx.x, lane = tid & 63, wid = tid >> 6;
  int rl = lane & 15, rq = lane >> 4;

  f32x4 acc[2][4] = {};
  for (int rep = 0; rep < reps; ++rep) {
    #pragma unroll
    for (int j = 0; j < 8; ++j) {
      int g = tid + j * 256;                 // 0..2047
      int row = g >> 5;                      // 0..63
      int c = g & 31;                        // 16B chunk in 512B row
      int sc = c ^ (row & 7);
      int ldsbase = (wid * 64 + j * 256) * 16;   // wave-uniform
      GLOAD16(Bt + (size_t)row * V_DIM + sc * 8, Bsp + ldsbase);
    }

    short8 a[2][8];
    #pragma unroll
    for (int m = 0; m < 2; ++m)
      #pragma unroll
      for (int k = 0; k < 8; ++k)
        a[m][k] = *(const short8*)(Sc + (size_t)(wid * 32 + m * 16 + rl) * V_DIM
                                   + k * 32 + rq * 8);
    __syncthreads();

    #pragma unroll
    for (int k = 0; k < 8; ++k) {
      #pragma unroll
      for (int n = 0; n < 4; ++n) {
        int row = n * 16 + rl;
        short8 b = *(const short8*)(Bsp + row * 512
                                    + ((k * 64 + rq * 16) ^ ((row & 7) << 4)));
        acc[0][n] = MFMA16B(a[0][k], b, acc[0][n]);
        acc[1][n] = MFMA16B(a[1][k], b, acc[1][n]);
      }
    }
    __syncthreads();                         // WAR: next rep restages LDS
  }

  float* dst = outneg + ((size_t)p * U_DIM + my * 128) * F_DIM;
  #pragma unroll
  for (int m = 0; m < 2; ++m)
    #pragma unroll
    for (int n = 0; n < 4; ++n)
      #pragma unroll
      for (int i = 0; i < 4; ++i) {
        int u = wid * 32 + m * 16 + rq * 4 + i;
        int f = n0 + n * 16 + rl;
        dst[(size_t)u * F_DIM + f] = acc[m][n][i] * scale;
      }
}

// ---------------------------------------------------------------------------
extern "C" void kernel_launch(void* const* d_in, const int* in_sizes, int n_in,
                              void* d_out, int out_size, void* d_ws, size_t ws_size,
                              hipStream_t stream) {
  const float* fu = (const float*)d_in[0];
  const float* fv = (const float*)d_in[1];
  float* out = (float*)d_out;
  char* ws = (char*)d_ws;

  // ws: vv 8KB | score 1MB | fvT 51.4MB | fuH 51.4MB | fvH 51.4MB |
  //     vvpart 1.6MB | part (splitk * 2MB)
  const size_t HVF = (size_t)P_DIM * F_DIM * V_DIM * 2;   // 51,380,224
  float* vv = (float*)ws;
  unsigned short* score = (unsigned short*)(ws + 8192);
  unsigned short* fvT = (unsigned short*)(ws + 8192 + 1048576);
  unsigned short* fuH = (unsigned short*)(ws + 8192 + 1048576 + HVF);
  unsigned short* fvH = (unsigned short*)(ws + 8192 + 1048576 + 2 * HVF);
  size_t vvpartBase = 8192 + 1048576 + 3 * HVF;
  float* vvpart = (float*)(ws + vvpartBase);
  size_t partBase = vvpartBase + (size_t)(F_DIM / 64) * P_DIM * V_DIM * 4;
  float* part = (float*)(ws + partBase);

  const size_t puv4 = (size_t)P_DIM * U_DIM * V_DIM * 4;
  int splitk = 1;
  const int cands[5] = {14, 7, 4, 2, 1};     // all divide 196 -> chunk % 64 == 0
  for (int i = 0; i < 5; ++i) {
    if (partBase + (size_t)cands[i] * puv4 <= ws_size) { splitk = cands[i]; break; }
  }
  int chunk = F_DIM / splitk;

  const int UV_REPS = 4;                     // diagnostic amplification (pow2!)
  const float UV_SCALE = 1.0f / UV_REPS;
  const int PV_REPS = 16;
  const float PV_SCALE = 1.0f / PV_REPS;

  prep_fv<<<dim3(F_DIM / 64, V_DIM / 64, P_DIM), 256, 0, stream>>>(fv, fvT, fvH,
                                                                   vvpart);
  vv_reduce<<<P_DIM * 4, 256, 0, stream>>>(vvpart, vv);
  int n4 = (P_DIM * U_DIM * F_DIM) / 4;
  copy_fu<<<2048, 256, 0, stream>>>((const float4*)fu, (float4*)out,
                                    (ushort4*)fuH, n4);
  uv_gemm<<<splitk * 32, 256, 0, stream>>>(fuH, fvH, part, splitk, chunk,
                                           UV_REPS, UV_SCALE);
  reduce_softmax<<<P_DIM * U_DIM, 256, 0, stream>>>(part, vv, score, splitk);
  pv_gemm<<<dim3(2, F_DIM / 64, P_DIM), 256, 0, stream>>>(
      score, fvT, out + (size_t)P_DIM * U_DIM * F_DIM, PV_REPS, PV_SCALE);
}

// Round 20
// 206.984 us; speedup vs baseline: 1.7059x; 1.7059x over previous
//
#include <hip/hip_runtime.h>
#include <cstdint>
#include <cstddef>

#define P_DIM 8
#define U_DIM 256
#define V_DIM 256
#define F_DIM 12544   // 256*49

typedef __attribute__((ext_vector_type(8))) short short8;
typedef __attribute__((ext_vector_type(8))) _Float16 half8;
typedef __attribute__((ext_vector_type(4))) float f32x4;

#define MFMA16B(a, b, c) __builtin_amdgcn_mfma_f32_16x16x32_bf16((a), (b), (c), 0, 0, 0)
#define MFMA16H(a, b, c) __builtin_amdgcn_mfma_f32_16x16x32_f16((a), (b), (c), 0, 0, 0)

// async global->LDS, 16B per lane; LDS dest must be the wave-uniform base
#define GLOAD16(gsrc, ldsbase)                                                \
  __builtin_amdgcn_global_load_lds(                                           \
      (const __attribute__((address_space(1))) void*)(gsrc),                  \
      (__attribute__((address_space(3))) void*)(ldsbase), 16, 0, 0)

__device__ __forceinline__ unsigned short f2bf(float x) {      // RNE
  unsigned u = __builtin_bit_cast(unsigned, x);
  u += 0x7FFFu + ((u >> 16) & 1u);
  return (unsigned short)(u >> 16);
}
__device__ __forceinline__ unsigned short f2h(float x) {       // RNE fp16
  return __builtin_bit_cast(unsigned short, (_Float16)x);
}

// ---------------------------------------------------------------------------
// 1) prep_fv: reads fv ONCE; writes fvT bf16 [p][f][v], fvH fp16 [p][v][f],
//    fp32 vv partials.   (R15-identical)
// ---------------------------------------------------------------------------
__global__ __launch_bounds__(256) void prep_fv(const float* __restrict__ fv,
                                               unsigned short* __restrict__ fvT,
                                               unsigned short* __restrict__ fvH,
                                               float* __restrict__ vvpart) {
  __shared__ unsigned short tile[64][65];
  __shared__ float vvp[64];
  int f0 = blockIdx.x * 64, v0 = blockIdx.y * 64, p = blockIdx.z;
  const float* src = fv + (size_t)p * V_DIM * F_DIM;
  unsigned short* dstH = fvH + (size_t)p * V_DIM * F_DIM;
  int t = threadIdx.x;
  #pragma unroll
  for (int i = 0; i < 4; ++i) {
    int g = t + i * 256;                     // 0..1023
    int r = g >> 4;                          // v row 0..63
    int c4 = (g & 15) * 4;                   // f col
    float4 x = *(const float4*)(src + (size_t)(v0 + r) * F_DIM + f0 + c4);
    tile[r][c4 + 0] = f2bf(x.x);
    tile[r][c4 + 1] = f2bf(x.y);
    tile[r][c4 + 2] = f2bf(x.z);
    tile[r][c4 + 3] = f2bf(x.w);
    ushort4 h;
    h.x = f2h(x.x); h.y = f2h(x.y); h.z = f2h(x.z); h.w = f2h(x.w);
    *(ushort4*)(dstH + (size_t)(v0 + r) * F_DIM + f0 + c4) = h;
    float ps = x.x * x.x + x.y * x.y + x.z * x.z + x.w * x.w;
    ps += __shfl_xor(ps, 1); ps += __shfl_xor(ps, 2);
    ps += __shfl_xor(ps, 4); ps += __shfl_xor(ps, 8);
    if ((t & 15) == 0) vvp[r] = ps;
  }
  __syncthreads();
  if (t < 64)
    vvpart[((size_t)blockIdx.x * P_DIM + p) * V_DIM + v0 + t] = vvp[t];
  unsigned short* dst = fvT + (size_t)p * F_DIM * V_DIM;
  #pragma unroll
  for (int i = 0; i < 2; ++i) {
    int g = t + i * 256;                     // 0..511
    int f = g >> 3;                          // 0..63
    int v8 = (g & 7) * 8;
    short8 o;
    #pragma unroll
    for (int j = 0; j < 8; ++j) o[j] = (short)tile[v8 + j][f];
    *(short8*)(dst + (size_t)(f0 + f) * V_DIM + v0 + v8) = o;
  }
}

// ---------------------------------------------------------------------------
// 2) vv_reduce: 32 blocks, 4-way k-split per block
// ---------------------------------------------------------------------------
__global__ __launch_bounds__(256) void vv_reduce(const float* __restrict__ vvpart,
                                                 float* __restrict__ vv) {
  int p = blockIdx.x >> 2;
  int vb = (blockIdx.x & 3) * 64;
  int vl = threadIdx.x & 63;
  int v = vb + vl;
  int js = threadIdx.x >> 6;                 // 0..3
  float s = 0.f;
  for (int j = js; j < F_DIM / 64; j += 4)
    s += vvpart[((size_t)j * P_DIM + p) * V_DIM + v];
  __shared__ float red[4][64];
  red[js][vl] = s;
  __syncthreads();
  if (threadIdx.x < 64)
    vv[p * V_DIM + v] = red[0][vl] + red[1][vl] + red[2][vl] + red[3][vl];
}

// ---------------------------------------------------------------------------
// 3) copy_fu: feat_u -> out[0 : P*U*F] (fp32) AND fuH fp16 [p][u][f]
// ---------------------------------------------------------------------------
__global__ __launch_bounds__(256) void copy_fu(const float4* __restrict__ src,
                                               float4* __restrict__ dst,
                                               ushort4* __restrict__ fuH, int n4) {
  for (int i = blockIdx.x * 256 + threadIdx.x; i < n4; i += gridDim.x * 256) {
    float4 x = src[i];
    dst[i] = x;
    ushort4 h;
    h.x = f2h(x.x); h.y = f2h(x.y); h.z = f2h(x.z); h.w = f2h(x.w);
    fuH[i] = h;
  }
}

// ---------------------------------------------------------------------------
// 4) uv_gemm v13 (R15-identical, T_uv ~26us): fp16 inputs, T14 reg-stage +
//    dbuf, 128x128 tile, BK=64, 64 KB LDS, splitk=14 (grid 448).
// ---------------------------------------------------------------------------
__global__ __launch_bounds__(256, 2) void uv_gemm(const unsigned short* __restrict__ fuH,
                                                  const unsigned short* __restrict__ fvH,
                                                  float* __restrict__ part,
                                                  int splitk, int chunk) {
  // bijective XCD chunk swizzle (m204)
  int nwg = gridDim.x;
  int q = nwg >> 3, r = nwg & 7;
  int xcd = blockIdx.x & 7, ofs = blockIdx.x >> 3;
  int wgid = (xcd < r ? xcd * (q + 1) : r * (q + 1) + (xcd - r) * q) + ofs;
  int nt = wgid & 1, mt = (wgid >> 1) & 1, p = (wgid >> 2) & 7, ks = wgid >> 5;

  const unsigned short* A = fuH + ((size_t)p * U_DIM + mt * 128) * F_DIM;
  const unsigned short* B = fvH + ((size_t)p * V_DIM + nt * 128) * F_DIM;
  int k0 = ks * chunk;
  int nkt = chunk >> 6;

  __shared__ short AS[2][128 * 64], BS[2][128 * 64];   // 64 KB (fp16, dbuf)

  int tid = threadIdx.x, lane = tid & 63, wid = tid >> 6;
  int wm = wid >> 1, wn = wid & 1;           // 2x2 waves, 64x64 each
  int rl = lane & 15;
  f32x4 acc[4][4] = {};
  short8 ra[4], rb[4];                       // staged tile regs (32 VGPR)

#define LOADR(kg)                                                             \
  do {                                                                        \
    _Pragma("unroll") for (int j = 0; j < 4; ++j) {                           \
      int g = tid + j * 256;                                                  \
      int row = g >> 3, c = g & 7;                                            \
      ra[j] = *(const short8*)(A + (size_t)row * F_DIM + (kg) + c * 8);       \
      rb[j] = *(const short8*)(B + (size_t)row * F_DIM + (kg) + c * 8);       \
    }                                                                         \
  } while (0)

#define WRITES(buf)                                                           \
  do {                                                                        \
    _Pragma("unroll") for (int j = 0; j < 4; ++j) {                           \
      int g = tid + j * 256;                                                  \
      int row = g >> 3, c = g & 7;                                            \
      int off = (row * 128 + c * 16) ^ ((row & 7) << 4);                      \
      *(short8*)((char*)AS[buf] + off) = ra[j];                               \
      *(short8*)((char*)BS[buf] + off) = rb[j];                               \
    }                                                                         \
  } while (0)

  LOADR(k0);
  WRITES(0);
  __syncthreads();
  int cur = 0;
  for (int kt = 0; kt < nkt; ++kt) {
    bool more = (kt + 1 < nkt);
    if (more) LOADR(k0 + (kt + 1) * 64);     // issue EARLY (T14)
    const char* Ap = (const char*)AS[cur];
    const char* Bp = (const char*)BS[cur];
    #pragma unroll
    for (int kk = 0; kk < 2; ++kk) {
      int kbyte = kk * 64 + (lane >> 4) * 16;
      half8 ah[4], bh[4];
      #pragma unroll
      for (int m = 0; m < 4; ++m) {
        int row = wm * 64 + m * 16 + rl;
        int off = (row * 128 + kbyte) ^ ((row & 7) << 4);
        ah[m] = *(const half8*)(Ap + off);
      }
      #pragma unroll
      for (int n = 0; n < 4; ++n) {
        int row = wn * 64 + n * 16 + rl;
        int off = (row * 128 + kbyte) ^ ((row & 7) << 4);
        bh[n] = *(const half8*)(Bp + off);
      }
      #pragma unroll
      for (int m = 0; m < 4; ++m)
        #pragma unroll
        for (int n = 0; n < 4; ++n)
          acc[m][n] = MFMA16H(ah[m], bh[n], acc[m][n]);
    }
    if (more) WRITES(cur ^ 1);               // write LATE (vmcnt lands here)
    __syncthreads();
    cur ^= 1;
  }
#undef LOADR
#undef WRITES
  float* dst = part + ((size_t)ks * P_DIM + p) * U_DIM * V_DIM;
  int rq = lane >> 4;
  #pragma unroll
  for (int m = 0; m < 4; ++m)
    #pragma unroll
    for (int n = 0; n < 4; ++n)
      #pragma unroll
      for (int i = 0; i < 4; ++i) {
        int u = mt * 128 + wm * 64 + m * 16 + rq * 4 + i;
        int v = nt * 128 + wn * 64 + n * 16 + rl;
        dst[(size_t)u * V_DIM + v] = acc[m][n][i];
      }
}

// ---------------------------------------------------------------------------
// 5) reduce partials + softmax over v -> bf16 score.  logit = 0.1*vv - 0.2*uv
// ---------------------------------------------------------------------------
__global__ __launch_bounds__(256) void reduce_softmax(const float* __restrict__ part,
                                                      const float* __restrict__ vv,
                                                      unsigned short* __restrict__ score,
                                                      int splitk) {
  int u = blockIdx.x & 255, p = blockIdx.x >> 8;
  int v = threadIdx.x;
  size_t base = ((size_t)p * U_DIM + u) * V_DIM + v;
  float s = 0.f;
  for (int k = 0; k < splitk; ++k)
    s += part[(size_t)k * (P_DIM * U_DIM * V_DIM) + base];
  float logit = 0.1f * vv[p * V_DIM + v] - 0.2f * s;
  float m = logit;
  #pragma unroll
  for (int off = 32; off >= 1; off >>= 1) m = fmaxf(m, __shfl_xor(m, off));
  __shared__ float red[4], red2[4];
  int lane = v & 63, wid = v >> 6;
  if (lane == 0) red[wid] = m;
  __syncthreads();
  m = fmaxf(fmaxf(red[0], red[1]), fmaxf(red[2], red[3]));
  float e = __expf(logit - m);
  float tsum = e;
  #pragma unroll
  for (int off = 32; off >= 1; off >>= 1) tsum += __shfl_xor(tsum, off);
  if (lane == 0) red2[wid] = tsum;
  __syncthreads();
  tsum = red2[0] + red2[1] + red2[2] + red2[3];
  score[base] = f2bf(e / tsum);
}

// ---------------------------------------------------------------------------
// 6) pv_gemm v7: BM=256 (all u -> fvT read ONCE), BN=64 f, full K=256.
//    SWAPPED MFMA operands: mfma(fvT_frag, score_frag, acc) puts f on the
//    D-row axis -> each lane's acc quad = 4 CONSECUTIVE f at one u ->
//    coalesced global_store_dwordx4 (16 stores/thread vs 32 scalar).
//    Score frags 2-deep ping-pong (static idx); k=0 frags issued before the
//    barrier to overlap the gload_lds staging.  grid (196, 8) x 256.
// ---------------------------------------------------------------------------
__global__ __launch_bounds__(256, 2) void pv_gemm(const unsigned short* __restrict__ score,
                                                  const unsigned short* __restrict__ fvT,
                                                  float* __restrict__ outneg) {
  int bx = blockIdx.x;                       // f tile 0..195 (64 wide)
  int p = blockIdx.y;
  int n0 = bx * 64;
  const unsigned short* Sc = score + (size_t)p * U_DIM * V_DIM;
  const unsigned short* Bt = fvT + ((size_t)p * F_DIM + n0) * V_DIM;
  __shared__ short Bs[64 * 256];             // 32 KB, swizzled
  char* Bsp = (char*)Bs;
  int tid = threadIdx.x, lane = tid & 63, wid = tid >> 6;
  int rl = lane & 15, rq = lane >> 4;

  // stage fvT tile via async global->LDS (source-swizzled, linear dest)
  #pragma unroll
  for (int j = 0; j < 8; ++j) {
    int g = tid + j * 256;                   // 0..2047
    int row = g >> 5;                        // 0..63
    int c = g & 31;                          // 16B chunk in 512B row
    int sc = c ^ (row & 7);
    int ldsbase = (wid * 64 + j * 256) * 16; // wave-uniform
    GLOAD16(Bt + (size_t)row * V_DIM + sc * 8, Bsp + ldsbase);
  }

  // wave wid owns u rows [wid*64, wid*64+64)
  const unsigned short* ScW = Sc + (size_t)(wid * 64) * V_DIM;
  short8 sc0[4], sc1[4];
  #pragma unroll
  for (int nu = 0; nu < 4; ++nu)             // k=0 frags: overlap staging
    sc0[nu] = *(const short8*)(ScW + (size_t)(nu * 16 + rl) * V_DIM + rq * 8);
  __syncthreads();

  f32x4 acc[4][4] = {};                      // [mf][nu]
  #pragma unroll
  for (int k = 0; k < 8; ++k) {
    if (k + 1 < 8) {                         // prefetch next k (ping-pong)
      if ((k & 1) == 0) {
        #pragma unroll
        for (int nu = 0; nu < 4; ++nu)
          sc1[nu] = *(const short8*)(ScW + (size_t)(nu * 16 + rl) * V_DIM
                                     + (k + 1) * 32 + rq * 8);
      } else {
        #pragma unroll
        for (int nu = 0; nu < 4; ++nu)
          sc0[nu] = *(const short8*)(ScW + (size_t)(nu * 16 + rl) * V_DIM
                                     + (k + 1) * 32 + rq * 8);
      }
    }
    short8 fvf[4];
    #pragma unroll
    for (int mf = 0; mf < 4; ++mf) {
      int row = mf * 16 + rl;
      fvf[mf] = *(const short8*)(Bsp + row * 512
                                 + ((k * 64 + rq * 16) ^ ((row & 7) << 4)));
    }
    #pragma unroll
    for (int mf = 0; mf < 4; ++mf)
      #pragma unroll
      for (int nu = 0; nu < 4; ++nu)
        acc[mf][nu] = MFMA16B(fvf[mf], ((k & 1) == 0 ? sc0 : sc1)[nu],
                              acc[mf][nu]);
  }

  // store: u = col(rl), f = row(rq*4+i) -> f32x4 per (mf,nu), 16B coalesced
  float* dst = outneg + (size_t)p * U_DIM * F_DIM;
  #pragma unroll
  for (int mf = 0; mf < 4; ++mf)
    #pragma unroll
    for (int nu = 0; nu < 4; ++nu) {
      int u = wid * 64 + nu * 16 + rl;
      int f = n0 + mf * 16 + rq * 4;
      *(f32x4*)(dst + (size_t)u * F_DIM + f) = acc[mf][nu];
    }
}

// ---------------------------------------------------------------------------
extern "C" void kernel_launch(void* const* d_in, const int* in_sizes, int n_in,
                              void* d_out, int out_size, void* d_ws, size_t ws_size,
                              hipStream_t stream) {
  const float* fu = (const float*)d_in[0];
  const float* fv = (const float*)d_in[1];
  float* out = (float*)d_out;
  char* ws = (char*)d_ws;

  // ws: vv 8KB | score 1MB | fvT 51.4MB | fuH 51.4MB | fvH 51.4MB |
  //     vvpart 1.6MB | part (splitk * 2MB)
  const size_t HVF = (size_t)P_DIM * F_DIM * V_DIM * 2;   // 51,380,224
  float* vv = (float*)ws;
  unsigned short* score = (unsigned short*)(ws + 8192);
  unsigned short* fvT = (unsigned short*)(ws + 8192 + 1048576);
  unsigned short* fuH = (unsigned short*)(ws + 8192 + 1048576 + HVF);
  unsigned short* fvH = (unsigned short*)(ws + 8192 + 1048576 + 2 * HVF);
  size_t vvpartBase = 8192 + 1048576 + 3 * HVF;
  float* vvpart = (float*)(ws + vvpartBase);
  size_t partBase = vvpartBase + (size_t)(F_DIM / 64) * P_DIM * V_DIM * 4;
  float* part = (float*)(ws + partBase);

  const size_t puv4 = (size_t)P_DIM * U_DIM * V_DIM * 4;
  int splitk = 1;
  const int cands[5] = {14, 7, 4, 2, 1};     // all divide 196 -> chunk % 64 == 0
  for (int i = 0; i < 5; ++i) {
    if (partBase + (size_t)cands[i] * puv4 <= ws_size) { splitk = cands[i]; break; }
  }
  int chunk = F_DIM / splitk;

  prep_fv<<<dim3(F_DIM / 64, V_DIM / 64, P_DIM), 256, 0, stream>>>(fv, fvT, fvH,
                                                                   vvpart);
  vv_reduce<<<P_DIM * 4, 256, 0, stream>>>(vvpart, vv);
  int n4 = (P_DIM * U_DIM * F_DIM) / 4;
  copy_fu<<<2048, 256, 0, stream>>>((const float4*)fu, (float4*)out,
                                    (ushort4*)fuH, n4);
  uv_gemm<<<splitk * 32, 256, 0, stream>>>(fuH, fvH, part, splitk, chunk);
  reduce_softmax<<<P_DIM * U_DIM, 256, 0, stream>>>(part, vv, score, splitk);
  pv_gemm<<<dim3(F_DIM / 64, P_DIM), 256, 0, stream>>>(
      score, fvT, out + (size_t)P_DIM * U_DIM * F_DIM);
}

// Round 22
// 181.078 us; speedup vs baseline: 1.9500x; 1.1431x over previous
//
#include <hip/hip_runtime.h>
#include <cstdint>
#include <cstddef>

#define P_DIM 8
#define U_DIM 256
#define V_DIM 256
#define F_DIM 12544   // 256*49

typedef __attribute__((ext_vector_type(8))) short short8;
typedef __attribute__((ext_vector_type(8))) _Float16 half8;
typedef __attribute__((ext_vector_type(4))) float f32x4;

#define MFMA16B(a, b, c) __builtin_amdgcn_mfma_f32_16x16x32_bf16((a), (b), (c), 0, 0, 0)
#define MFMA16H(a, b, c) __builtin_amdgcn_mfma_f32_16x16x32_f16((a), (b), (c), 0, 0, 0)

// async global->LDS, 16B per lane; LDS dest must be the wave-uniform base
#define GLOAD16(gsrc, ldsbase)                                                \
  __builtin_amdgcn_global_load_lds(                                           \
      (const __attribute__((address_space(1))) void*)(gsrc),                  \
      (__attribute__((address_space(3))) void*)(ldsbase), 16, 0, 0)

__device__ __forceinline__ unsigned short f2bf(float x) {      // RNE
  unsigned u = __builtin_bit_cast(unsigned, x);
  u += 0x7FFFu + ((u >> 16) & 1u);
  return (unsigned short)(u >> 16);
}
__device__ __forceinline__ unsigned short f2h(float x) {       // RNE fp16
  return __builtin_bit_cast(unsigned short, (_Float16)x);
}

// ---------------------------------------------------------------------------
// 1) copy_fu (runs FIRST): feat_u -> out[0:P*U*F] (fp32, NT stores) + fuH fp16
// ---------------------------------------------------------------------------
__global__ __launch_bounds__(256) void copy_fu(const float4* __restrict__ src,
                                               float4* __restrict__ dst,
                                               ushort4* __restrict__ fuH, int n4) {
  for (int i = blockIdx.x * 256 + threadIdx.x; i < n4; i += gridDim.x * 256) {
    float4 x = src[i];
    // nt builtin needs ext-vector type, not HIP_vector_type
    __builtin_nontemporal_store(__builtin_bit_cast(f32x4, x), (f32x4*)&dst[i]);
    ushort4 h;
    h.x = f2h(x.x); h.y = f2h(x.y); h.z = f2h(x.z); h.w = f2h(x.w);
    fuH[i] = h;
  }
}

// ---------------------------------------------------------------------------
// 2) prep_fv: reads fv ONCE; writes fvT bf16 [p][f][v], fvH fp16 [p][v][f],
//    fp32 vv partials.  (Runs AFTER copy so fvT stays L3-hot for pv.)
// ---------------------------------------------------------------------------
__global__ __launch_bounds__(256) void prep_fv(const float* __restrict__ fv,
                                               unsigned short* __restrict__ fvT,
                                               unsigned short* __restrict__ fvH,
                                               float* __restrict__ vvpart) {
  __shared__ unsigned short tile[64][65];
  __shared__ float vvp[64];
  int f0 = blockIdx.x * 64, v0 = blockIdx.y * 64, p = blockIdx.z;
  const float* src = fv + (size_t)p * V_DIM * F_DIM;
  unsigned short* dstH = fvH + (size_t)p * V_DIM * F_DIM;
  int t = threadIdx.x;
  #pragma unroll
  for (int i = 0; i < 4; ++i) {
    int g = t + i * 256;                     // 0..1023
    int r = g >> 4;                          // v row 0..63
    int c4 = (g & 15) * 4;                   // f col
    float4 x = *(const float4*)(src + (size_t)(v0 + r) * F_DIM + f0 + c4);
    tile[r][c4 + 0] = f2bf(x.x);
    tile[r][c4 + 1] = f2bf(x.y);
    tile[r][c4 + 2] = f2bf(x.z);
    tile[r][c4 + 3] = f2bf(x.w);
    ushort4 h;
    h.x = f2h(x.x); h.y = f2h(x.y); h.z = f2h(x.z); h.w = f2h(x.w);
    *(ushort4*)(dstH + (size_t)(v0 + r) * F_DIM + f0 + c4) = h;
    float ps = x.x * x.x + x.y * x.y + x.z * x.z + x.w * x.w;
    ps += __shfl_xor(ps, 1); ps += __shfl_xor(ps, 2);
    ps += __shfl_xor(ps, 4); ps += __shfl_xor(ps, 8);
    if ((t & 15) == 0) vvp[r] = ps;
  }
  __syncthreads();
  if (t < 64)
    vvpart[((size_t)blockIdx.x * P_DIM + p) * V_DIM + v0 + t] = vvp[t];
  unsigned short* dst = fvT + (size_t)p * F_DIM * V_DIM;
  #pragma unroll
  for (int i = 0; i < 2; ++i) {
    int g = t + i * 256;                     // 0..511
    int f = g >> 3;                          // 0..63
    int v8 = (g & 7) * 8;
    short8 o;
    #pragma unroll
    for (int j = 0; j < 8; ++j) o[j] = (short)tile[v8 + j][f];
    *(short8*)(dst + (size_t)(f0 + f) * V_DIM + v0 + v8) = o;
  }
}

// ---------------------------------------------------------------------------
// 3) vv_reduce: 32 blocks, 4-way k-split per block
// ---------------------------------------------------------------------------
__global__ __launch_bounds__(256) void vv_reduce(const float* __restrict__ vvpart,
                                                 float* __restrict__ vv) {
  int p = blockIdx.x >> 2;
  int vb = (blockIdx.x & 3) * 64;
  int vl = threadIdx.x & 63;
  int v = vb + vl;
  int js = threadIdx.x >> 6;                 // 0..3
  float s = 0.f;
  for (int j = js; j < F_DIM / 64; j += 4)
    s += vvpart[((size_t)j * P_DIM + p) * V_DIM + v];
  __shared__ float red[4][64];
  red[js][vl] = s;
  __syncthreads();
  if (threadIdx.x < 64)
    vv[p * V_DIM + v] = red[0][vl] + red[1][vl] + red[2][vl] + red[3][vl];
}

// ---------------------------------------------------------------------------
// 4) uv_gemm v13 (R15-identical, T_uv ~26-28us): fp16 inputs, T14 reg-stage +
//    dbuf, 128x128 tile, BK=64, 64 KB LDS, splitk=14 (grid 448).
// ---------------------------------------------------------------------------
__global__ __launch_bounds__(256, 2) void uv_gemm(const unsigned short* __restrict__ fuH,
                                                  const unsigned short* __restrict__ fvH,
                                                  float* __restrict__ part,
                                                  int splitk, int chunk) {
  // bijective XCD chunk swizzle (m204)
  int nwg = gridDim.x;
  int q = nwg >> 3, r = nwg & 7;
  int xcd = blockIdx.x & 7, ofs = blockIdx.x >> 3;
  int wgid = (xcd < r ? xcd * (q + 1) : r * (q + 1) + (xcd - r) * q) + ofs;
  int nt = wgid & 1, mt = (wgid >> 1) & 1, p = (wgid >> 2) & 7, ks = wgid >> 5;

  const unsigned short* A = fuH + ((size_t)p * U_DIM + mt * 128) * F_DIM;
  const unsigned short* B = fvH + ((size_t)p * V_DIM + nt * 128) * F_DIM;
  int k0 = ks * chunk;
  int nkt = chunk >> 6;

  __shared__ short AS[2][128 * 64], BS[2][128 * 64];   // 64 KB (fp16, dbuf)

  int tid = threadIdx.x, lane = tid & 63, wid = tid >> 6;
  int wm = wid >> 1, wn = wid & 1;           // 2x2 waves, 64x64 each
  int rl = lane & 15;
  f32x4 acc[4][4] = {};
  short8 ra[4], rb[4];                       // staged tile regs (32 VGPR)

#define LOADR(kg)                                                             \
  do {                                                                        \
    _Pragma("unroll") for (int j = 0; j < 4; ++j) {                           \
      int g = tid + j * 256;                                                  \
      int row = g >> 3, c = g & 7;                                            \
      ra[j] = *(const short8*)(A + (size_t)row * F_DIM + (kg) + c * 8);       \
      rb[j] = *(const short8*)(B + (size_t)row * F_DIM + (kg) + c * 8);       \
    }                                                                         \
  } while (0)

#define WRITES(buf)                                                           \
  do {                                                                        \
    _Pragma("unroll") for (int j = 0; j < 4; ++j) {                           \
      int g = tid + j * 256;                                                  \
      int row = g >> 3, c = g & 7;                                            \
      int off = (row * 128 + c * 16) ^ ((row & 7) << 4);                      \
      *(short8*)((char*)AS[buf] + off) = ra[j];                               \
      *(short8*)((char*)BS[buf] + off) = rb[j];                               \
    }                                                                         \
  } while (0)

  LOADR(k0);
  WRITES(0);
  __syncthreads();
  int cur = 0;
  for (int kt = 0; kt < nkt; ++kt) {
    bool more = (kt + 1 < nkt);
    if (more) LOADR(k0 + (kt + 1) * 64);     // issue EARLY (T14)
    const char* Ap = (const char*)AS[cur];
    const char* Bp = (const char*)BS[cur];
    #pragma unroll
    for (int kk = 0; kk < 2; ++kk) {
      int kbyte = kk * 64 + (lane >> 4) * 16;
      half8 ah[4], bh[4];
      #pragma unroll
      for (int m = 0; m < 4; ++m) {
        int row = wm * 64 + m * 16 + rl;
        int off = (row * 128 + kbyte) ^ ((row & 7) << 4);
        ah[m] = *(const half8*)(Ap + off);
      }
      #pragma unroll
      for (int n = 0; n < 4; ++n) {
        int row = wn * 64 + n * 16 + rl;
        int off = (row * 128 + kbyte) ^ ((row & 7) << 4);
        bh[n] = *(const half8*)(Bp + off);
      }
      #pragma unroll
      for (int m = 0; m < 4; ++m)
        #pragma unroll
        for (int n = 0; n < 4; ++n)
          acc[m][n] = MFMA16H(ah[m], bh[n], acc[m][n]);
    }
    if (more) WRITES(cur ^ 1);               // write LATE (vmcnt lands here)
    __syncthreads();
    cur ^= 1;
  }
#undef LOADR
#undef WRITES
  float* dst = part + ((size_t)ks * P_DIM + p) * U_DIM * V_DIM;
  int rq = lane >> 4;
  #pragma unroll
  for (int m = 0; m < 4; ++m)
    #pragma unroll
    for (int n = 0; n < 4; ++n)
      #pragma unroll
      for (int i = 0; i < 4; ++i) {
        int u = mt * 128 + wm * 64 + m * 16 + rq * 4 + i;
        int v = nt * 128 + wn * 64 + n * 16 + rl;
        dst[(size_t)u * V_DIM + v] = acc[m][n][i];
      }
}

// ---------------------------------------------------------------------------
// 5) reduce partials + softmax over v -> bf16 score.  logit = 0.1*vv - 0.2*uv
// ---------------------------------------------------------------------------
__global__ __launch_bounds__(256) void reduce_softmax(const float* __restrict__ part,
                                                      const float* __restrict__ vv,
                                                      unsigned short* __restrict__ score,
                                                      int splitk) {
  int u = blockIdx.x & 255, p = blockIdx.x >> 8;
  int v = threadIdx.x;
  size_t base = ((size_t)p * U_DIM + u) * V_DIM + v;
  float s = 0.f;
  for (int k = 0; k < splitk; ++k)
    s += part[(size_t)k * (P_DIM * U_DIM * V_DIM) + base];
  float logit = 0.1f * vv[p * V_DIM + v] - 0.2f * s;
  float m = logit;
  #pragma unroll
  for (int off = 32; off >= 1; off >>= 1) m = fmaxf(m, __shfl_xor(m, off));
  __shared__ float red[4], red2[4];
  int lane = v & 63, wid = v >> 6;
  if (lane == 0) red[wid] = m;
  __syncthreads();
  m = fmaxf(fmaxf(red[0], red[1]), fmaxf(red[2], red[3]));
  float e = __expf(logit - m);
  float tsum = e;
  #pragma unroll
  for (int off = 32; off >= 1; off >>= 1) tsum += __shfl_xor(tsum, off);
  if (lane == 0) red2[wid] = tsum;
  __syncthreads();
  tsum = red2[0] + red2[1] + red2[2] + red2[3];
  score[base] = f2bf(e / tsum);
}

// ---------------------------------------------------------------------------
// 6) pv_gemm v8 = v6 structure + NONTEMPORAL stores (no L2/L3 write-allocate
//    thrash against the fvT stream) + launch_bounds (256,4) for 4-5 blk/CU.
//    128u x 64f x full K=256; gload_lds staged fvT; a-frags in regs; one
//    barrier.  grid (2, 196, 8) x 256.
// ---------------------------------------------------------------------------
__global__ __launch_bounds__(256, 4) void pv_gemm(const unsigned short* __restrict__ score,
                                                  const unsigned short* __restrict__ fvT,
                                                  float* __restrict__ outneg) {
  int my = blockIdx.x;                       // u half 0..1 (fastest)
  int bx = blockIdx.y;                       // f tile 0..195 (64 wide)
  int p = blockIdx.z;
  int n0 = bx * 64;
  const unsigned short* Sc = score + ((size_t)p * U_DIM + my * 128) * V_DIM;
  const unsigned short* Bt = fvT + ((size_t)p * F_DIM + n0) * V_DIM;
  __shared__ short Bs[64 * 256];             // 32 KB
  char* Bsp = (char*)Bs;
  int tid = threadIdx.x, lane = tid & 63, wid = tid >> 6;
  int rl = lane & 15, rq = lane >> 4;

  #pragma unroll
  for (int j = 0; j < 8; ++j) {
    int g = tid + j * 256;                   // 0..2047
    int row = g >> 5;                        // 0..63
    int c = g & 31;                          // 16B chunk in 512B row
    int sc = c ^ (row & 7);
    int ldsbase = (wid * 64 + j * 256) * 16; // wave-uniform
    GLOAD16(Bt + (size_t)row * V_DIM + sc * 8, Bsp + ldsbase);
  }

  short8 a[2][8];
  #pragma unroll
  for (int m = 0; m < 2; ++m)
    #pragma unroll
    for (int k = 0; k < 8; ++k)
      a[m][k] = *(const short8*)(Sc + (size_t)(wid * 32 + m * 16 + rl) * V_DIM
                                 + k * 32 + rq * 8);
  __syncthreads();

  f32x4 acc[2][4] = {};
  #pragma unroll
  for (int k = 0; k < 8; ++k) {
    #pragma unroll
    for (int n = 0; n < 4; ++n) {
      int row = n * 16 + rl;
      short8 b = *(const short8*)(Bsp + row * 512
                                  + ((k * 64 + rq * 16) ^ ((row & 7) << 4)));
      acc[0][n] = MFMA16B(a[0][k], b, acc[0][n]);
      acc[1][n] = MFMA16B(a[1][k], b, acc[1][n]);
    }
  }

  float* dst = outneg + ((size_t)p * U_DIM + my * 128) * F_DIM;
  #pragma unroll
  for (int m = 0; m < 2; ++m)
    #pragma unroll
    for (int n = 0; n < 4; ++n)
      #pragma unroll
      for (int i = 0; i < 4; ++i) {
        int u = wid * 32 + m * 16 + rq * 4 + i;
        int f = n0 + n * 16 + rl;
        __builtin_nontemporal_store(acc[m][n][i], &dst[(size_t)u * F_DIM + f]);
      }
}

// ---------------------------------------------------------------------------
extern "C" void kernel_launch(void* const* d_in, const int* in_sizes, int n_in,
                              void* d_out, int out_size, void* d_ws, size_t ws_size,
                              hipStream_t stream) {
  const float* fu = (const float*)d_in[0];
  const float* fv = (const float*)d_in[1];
  float* out = (float*)d_out;
  char* ws = (char*)d_ws;

  // ws: vv 8KB | score 1MB | fvT 51.4MB | fuH 51.4MB | fvH 51.4MB |
  //     vvpart 1.6MB | part (splitk * 2MB)
  const size_t HVF = (size_t)P_DIM * F_DIM * V_DIM * 2;   // 51,380,224
  float* vv = (float*)ws;
  unsigned short* score = (unsigned short*)(ws + 8192);
  unsigned short* fvT = (unsigned short*)(ws + 8192 + 1048576);
  unsigned short* fuH = (unsigned short*)(ws + 8192 + 1048576 + HVF);
  unsigned short* fvH = (unsigned short*)(ws + 8192 + 1048576 + 2 * HVF);
  size_t vvpartBase = 8192 + 1048576 + 3 * HVF;
  float* vvpart = (float*)(ws + vvpartBase);
  size_t partBase = vvpartBase + (size_t)(F_DIM / 64) * P_DIM * V_DIM * 4;
  float* part = (float*)(ws + partBase);

  const size_t puv4 = (size_t)P_DIM * U_DIM * V_DIM * 4;
  int splitk = 1;
  const int cands[5] = {14, 7, 4, 2, 1};     // all divide 196 -> chunk % 64 == 0
  for (int i = 0; i < 5; ++i) {
    if (partBase + (size_t)cands[i] * puv4 <= ws_size) { splitk = cands[i]; break; }
  }
  int chunk = F_DIM / splitk;

  int n4 = (P_DIM * U_DIM * F_DIM) / 4;
  copy_fu<<<2048, 256, 0, stream>>>((const float4*)fu, (float4*)out,
                                    (ushort4*)fuH, n4);
  prep_fv<<<dim3(F_DIM / 64, V_DIM / 64, P_DIM), 256, 0, stream>>>(fv, fvT, fvH,
                                                                   vvpart);
  vv_reduce<<<P_DIM * 4, 256, 0, stream>>>(vvpart, vv);
  uv_gemm<<<splitk * 32, 256, 0, stream>>>(fuH, fvH, part, splitk, chunk);
  reduce_softmax<<<P_DIM * U_DIM, 256, 0, stream>>>(part, vv, score, splitk);
  pv_gemm<<<dim3(2, F_DIM / 64, P_DIM), 256, 0, stream>>>(
      score, fvT, out + (size_t)P_DIM * U_DIM * F_DIM);
}

// Round 23
// 170.440 us; speedup vs baseline: 2.0717x; 1.0624x over previous
//
#include <hip/hip_runtime.h>
#include <cstdint>
#include <cstddef>

#define P_DIM 8
#define U_DIM 256
#define V_DIM 256
#define F_DIM 12544   // 256*49

typedef __attribute__((ext_vector_type(8))) short short8;
typedef __attribute__((ext_vector_type(8))) _Float16 half8;
typedef __attribute__((ext_vector_type(4))) float f32x4;

#define MFMA16B(a, b, c) __builtin_amdgcn_mfma_f32_16x16x32_bf16((a), (b), (c), 0, 0, 0)
#define MFMA16H(a, b, c) __builtin_amdgcn_mfma_f32_16x16x32_f16((a), (b), (c), 0, 0, 0)

// async global->LDS, 16B per lane; LDS dest must be the wave-uniform base
#define GLOAD16(gsrc, ldsbase)                                                \
  __builtin_amdgcn_global_load_lds(                                           \
      (const __attribute__((address_space(1))) void*)(gsrc),                  \
      (__attribute__((address_space(3))) void*)(ldsbase), 16, 0, 0)

__device__ __forceinline__ unsigned short f2bf(float x) {      // RNE
  unsigned u = __builtin_bit_cast(unsigned, x);
  u += 0x7FFFu + ((u >> 16) & 1u);
  return (unsigned short)(u >> 16);
}
__device__ __forceinline__ unsigned short f2h(float x) {       // RNE fp16
  return __builtin_bit_cast(unsigned short, (_Float16)x);
}

// nt load of 4 floats (ext-vector required by the builtin)
__device__ __forceinline__ float4 ntload4(const float* p) {
  f32x4 v = __builtin_nontemporal_load((const f32x4*)p);
  return __builtin_bit_cast(float4, v);
}

// ---------------------------------------------------------------------------
// 1) copy_fu (runs FIRST): feat_u -> out[0:P*U*F] (fp32) + fuH fp16.
//    NT loads (fu never re-read) + NT stores (out never re-read).
// ---------------------------------------------------------------------------
__global__ __launch_bounds__(256) void copy_fu(const float* __restrict__ src,
                                               float* __restrict__ dst,
                                               ushort4* __restrict__ fuH, int n4) {
  for (int i = blockIdx.x * 256 + threadIdx.x; i < n4; i += gridDim.x * 256) {
    float4 x = ntload4(src + (size_t)i * 4);
    __builtin_nontemporal_store(__builtin_bit_cast(f32x4, x),
                                (f32x4*)(dst + (size_t)i * 4));
    ushort4 h;
    h.x = f2h(x.x); h.y = f2h(x.y); h.z = f2h(x.z); h.w = f2h(x.w);
    fuH[i] = h;
  }
}

// ---------------------------------------------------------------------------
// 2) prep_fv: reads fv ONCE (NT loads); writes fvT bf16 [p][f][v], fvH fp16
//    [p][v][f], fp32 vv partials.  (After copy so intermediates stay L3-hot.)
// ---------------------------------------------------------------------------
__global__ __launch_bounds__(256) void prep_fv(const float* __restrict__ fv,
                                               unsigned short* __restrict__ fvT,
                                               unsigned short* __restrict__ fvH,
                                               float* __restrict__ vvpart) {
  __shared__ unsigned short tile[64][65];
  __shared__ float vvp[64];
  int f0 = blockIdx.x * 64, v0 = blockIdx.y * 64, p = blockIdx.z;
  const float* src = fv + (size_t)p * V_DIM * F_DIM;
  unsigned short* dstH = fvH + (size_t)p * V_DIM * F_DIM;
  int t = threadIdx.x;
  #pragma unroll
  for (int i = 0; i < 4; ++i) {
    int g = t + i * 256;                     // 0..1023
    int r = g >> 4;                          // v row 0..63
    int c4 = (g & 15) * 4;                   // f col
    float4 x = ntload4(src + (size_t)(v0 + r) * F_DIM + f0 + c4);
    tile[r][c4 + 0] = f2bf(x.x);
    tile[r][c4 + 1] = f2bf(x.y);
    tile[r][c4 + 2] = f2bf(x.z);
    tile[r][c4 + 3] = f2bf(x.w);
    ushort4 h;
    h.x = f2h(x.x); h.y = f2h(x.y); h.z = f2h(x.z); h.w = f2h(x.w);
    *(ushort4*)(dstH + (size_t)(v0 + r) * F_DIM + f0 + c4) = h;
    float ps = x.x * x.x + x.y * x.y + x.z * x.z + x.w * x.w;
    ps += __shfl_xor(ps, 1); ps += __shfl_xor(ps, 2);
    ps += __shfl_xor(ps, 4); ps += __shfl_xor(ps, 8);
    if ((t & 15) == 0) vvp[r] = ps;
  }
  __syncthreads();
  if (t < 64)
    vvpart[((size_t)blockIdx.x * P_DIM + p) * V_DIM + v0 + t] = vvp[t];
  unsigned short* dst = fvT + (size_t)p * F_DIM * V_DIM;
  #pragma unroll
  for (int i = 0; i < 2; ++i) {
    int g = t + i * 256;                     // 0..511
    int f = g >> 3;                          // 0..63
    int v8 = (g & 7) * 8;
    short8 o;
    #pragma unroll
    for (int j = 0; j < 8; ++j) o[j] = (short)tile[v8 + j][f];
    *(short8*)(dst + (size_t)(f0 + f) * V_DIM + v0 + v8) = o;
  }
}

// ---------------------------------------------------------------------------
// 3) vv_reduce: 32 blocks, 4-way k-split per block
// ---------------------------------------------------------------------------
__global__ __launch_bounds__(256) void vv_reduce(const float* __restrict__ vvpart,
                                                 float* __restrict__ vv) {
  int p = blockIdx.x >> 2;
  int vb = (blockIdx.x & 3) * 64;
  int vl = threadIdx.x & 63;
  int v = vb + vl;
  int js = threadIdx.x >> 6;                 // 0..3
  float s = 0.f;
  for (int j = js; j < F_DIM / 64; j += 4)
    s += vvpart[((size_t)j * P_DIM + p) * V_DIM + v];
  __shared__ float red[4][64];
  red[js][vl] = s;
  __syncthreads();
  if (threadIdx.x < 64)
    vv[p * V_DIM + v] = red[0][vl] + red[1][vl] + red[2][vl] + red[3][vl];
}

// ---------------------------------------------------------------------------
// 4) uv_gemm v13 (R22-identical): fp16 inputs, T14 reg-stage + dbuf,
//    128x128 tile, BK=64, 64 KB LDS, splitk=14 (grid 448).
// ---------------------------------------------------------------------------
__global__ __launch_bounds__(256, 2) void uv_gemm(const unsigned short* __restrict__ fuH,
                                                  const unsigned short* __restrict__ fvH,
                                                  float* __restrict__ part,
                                                  int splitk, int chunk) {
  // bijective XCD chunk swizzle (m204)
  int nwg = gridDim.x;
  int q = nwg >> 3, r = nwg & 7;
  int xcd = blockIdx.x & 7, ofs = blockIdx.x >> 3;
  int wgid = (xcd < r ? xcd * (q + 1) : r * (q + 1) + (xcd - r) * q) + ofs;
  int nt = wgid & 1, mt = (wgid >> 1) & 1, p = (wgid >> 2) & 7, ks = wgid >> 5;

  const unsigned short* A = fuH + ((size_t)p * U_DIM + mt * 128) * F_DIM;
  const unsigned short* B = fvH + ((size_t)p * V_DIM + nt * 128) * F_DIM;
  int k0 = ks * chunk;
  int nkt = chunk >> 6;

  __shared__ short AS[2][128 * 64], BS[2][128 * 64];   // 64 KB (fp16, dbuf)

  int tid = threadIdx.x, lane = tid & 63, wid = tid >> 6;
  int wm = wid >> 1, wn = wid & 1;           // 2x2 waves, 64x64 each
  int rl = lane & 15;
  f32x4 acc[4][4] = {};
  short8 ra[4], rb[4];                       // staged tile regs (32 VGPR)

#define LOADR(kg)                                                             \
  do {                                                                        \
    _Pragma("unroll") for (int j = 0; j < 4; ++j) {                           \
      int g = tid + j * 256;                                                  \
      int row = g >> 3, c = g & 7;                                            \
      ra[j] = *(const short8*)(A + (size_t)row * F_DIM + (kg) + c * 8);       \
      rb[j] = *(const short8*)(B + (size_t)row * F_DIM + (kg) + c * 8);       \
    }                                                                         \
  } while (0)

#define WRITES(buf)                                                           \
  do {                                                                        \
    _Pragma("unroll") for (int j = 0; j < 4; ++j) {                           \
      int g = tid + j * 256;                                                  \
      int row = g >> 3, c = g & 7;                                            \
      int off = (row * 128 + c * 16) ^ ((row & 7) << 4);                      \
      *(short8*)((char*)AS[buf] + off) = ra[j];                               \
      *(short8*)((char*)BS[buf] + off) = rb[j];                               \
    }                                                                         \
  } while (0)

  LOADR(k0);
  WRITES(0);
  __syncthreads();
  int cur = 0;
  for (int kt = 0; kt < nkt; ++kt) {
    bool more = (kt + 1 < nkt);
    if (more) LOADR(k0 + (kt + 1) * 64);     // issue EARLY (T14)
    const char* Ap = (const char*)AS[cur];
    const char* Bp = (const char*)BS[cur];
    #pragma unroll
    for (int kk = 0; kk < 2; ++kk) {
      int kbyte = kk * 64 + (lane >> 4) * 16;
      half8 ah[4], bh[4];
      #pragma unroll
      for (int m = 0; m < 4; ++m) {
        int row = wm * 64 + m * 16 + rl;
        int off = (row * 128 + kbyte) ^ ((row & 7) << 4);
        ah[m] = *(const half8*)(Ap + off);
      }
      #pragma unroll
      for (int n = 0; n < 4; ++n) {
        int row = wn * 64 + n * 16 + rl;
        int off = (row * 128 + kbyte) ^ ((row & 7) << 4);
        bh[n] = *(const half8*)(Bp + off);
      }
      #pragma unroll
      for (int m = 0; m < 4; ++m)
        #pragma unroll
        for (int n = 0; n < 4; ++n)
          acc[m][n] = MFMA16H(ah[m], bh[n], acc[m][n]);
    }
    if (more) WRITES(cur ^ 1);               // write LATE (vmcnt lands here)
    __syncthreads();
    cur ^= 1;
  }
#undef LOADR
#undef WRITES
  float* dst = part + ((size_t)ks * P_DIM + p) * U_DIM * V_DIM;
  int rq = lane >> 4;
  #pragma unroll
  for (int m = 0; m < 4; ++m)
    #pragma unroll
    for (int n = 0; n < 4; ++n)
      #pragma unroll
      for (int i = 0; i < 4; ++i) {
        int u = mt * 128 + wm * 64 + m * 16 + rq * 4 + i;
        int v = nt * 128 + wn * 64 + n * 16 + rl;
        dst[(size_t)u * V_DIM + v] = acc[m][n][i];
      }
}

// ---------------------------------------------------------------------------
// 5) reduce partials + softmax over v -> bf16 score.  logit = 0.1*vv - 0.2*uv
//    part is final-use here -> NT loads.
// ---------------------------------------------------------------------------
__global__ __launch_bounds__(256) void reduce_softmax(const float* __restrict__ part,
                                                      const float* __restrict__ vv,
                                                      unsigned short* __restrict__ score,
                                                      int splitk) {
  int u = blockIdx.x & 255, p = blockIdx.x >> 8;
  int v = threadIdx.x;
  size_t base = ((size_t)p * U_DIM + u) * V_DIM + v;
  float s = 0.f;
  for (int k = 0; k < splitk; ++k)
    s += __builtin_nontemporal_load(
        part + (size_t)k * (P_DIM * U_DIM * V_DIM) + base);
  float logit = 0.1f * vv[p * V_DIM + v] - 0.2f * s;
  float m = logit;
  #pragma unroll
  for (int off = 32; off >= 1; off >>= 1) m = fmaxf(m, __shfl_xor(m, off));
  __shared__ float red[4], red2[4];
  int lane = v & 63, wid = v >> 6;
  if (lane == 0) red[wid] = m;
  __syncthreads();
  m = fmaxf(fmaxf(red[0], red[1]), fmaxf(red[2], red[3]));
  float e = __expf(logit - m);
  float tsum = e;
  #pragma unroll
  for (int off = 32; off >= 1; off >>= 1) tsum += __shfl_xor(tsum, off);
  if (lane == 0) red2[wid] = tsum;
  __syncthreads();
  tsum = red2[0] + red2[1] + red2[2] + red2[3];
  score[base] = f2bf(e / tsum);
}

// ---------------------------------------------------------------------------
// 6) pv_gemm v8 (R22-identical): NT stores + (256,4); 128u x 64f x K=256;
//    gload_lds staged fvT; a-frags in regs; one barrier. grid (2,196,8).
// ---------------------------------------------------------------------------
__global__ __launch_bounds__(256, 4) void pv_gemm(const unsigned short* __restrict__ score,
                                                  const unsigned short* __restrict__ fvT,
                                                  float* __restrict__ outneg) {
  int my = blockIdx.x;                       // u half 0..1 (fastest)
  int bx = blockIdx.y;                       // f tile 0..195 (64 wide)
  int p = blockIdx.z;
  int n0 = bx * 64;
  const unsigned short* Sc = score + ((size_t)p * U_DIM + my * 128) * V_DIM;
  const unsigned short* Bt = fvT + ((size_t)p * F_DIM + n0) * V_DIM;
  __shared__ short Bs[64 * 256];             // 32 KB
  char* Bsp = (char*)Bs;
  int tid = threadIdx.x, lane = tid & 63, wid = tid >> 6;
  int rl = lane & 15, rq = lane >> 4;

  #pragma unroll
  for (int j = 0; j < 8; ++j) {
    int g = tid + j * 256;                   // 0..2047
    int row = g >> 5;                        // 0..63
    int c = g & 31;                          // 16B chunk in 512B row
    int sc = c ^ (row & 7);
    int ldsbase = (wid * 64 + j * 256) * 16; // wave-uniform
    GLOAD16(Bt + (size_t)row * V_DIM + sc * 8, Bsp + ldsbase);
  }

  short8 a[2][8];
  #pragma unroll
  for (int m = 0; m < 2; ++m)
    #pragma unroll
    for (int k = 0; k < 8; ++k)
      a[m][k] = *(const short8*)(Sc + (size_t)(wid * 32 + m * 16 + rl) * V_DIM
                                 + k * 32 + rq * 8);
  __syncthreads();

  f32x4 acc[2][4] = {};
  #pragma unroll
  for (int k = 0; k < 8; ++k) {
    #pragma unroll
    for (int n = 0; n < 4; ++n) {
      int row = n * 16 + rl;
      short8 b = *(const short8*)(Bsp + row * 512
                                  + ((k * 64 + rq * 16) ^ ((row & 7) << 4)));
      acc[0][n] = MFMA16B(a[0][k], b, acc[0][n]);
      acc[1][n] = MFMA16B(a[1][k], b, acc[1][n]);
    }
  }

  float* dst = outneg + ((size_t)p * U_DIM + my * 128) * F_DIM;
  #pragma unroll
  for (int m = 0; m < 2; ++m)
    #pragma unroll
    for (int n = 0; n < 4; ++n)
      #pragma unroll
      for (int i = 0; i < 4; ++i) {
        int u = wid * 32 + m * 16 + rq * 4 + i;
        int f = n0 + n * 16 + rl;
        __builtin_nontemporal_store(acc[m][n][i], &dst[(size_t)u * F_DIM + f]);
      }
}

// ---------------------------------------------------------------------------
extern "C" void kernel_launch(void* const* d_in, const int* in_sizes, int n_in,
                              void* d_out, int out_size, void* d_ws, size_t ws_size,
                              hipStream_t stream) {
  const float* fu = (const float*)d_in[0];
  const float* fv = (const float*)d_in[1];
  float* out = (float*)d_out;
  char* ws = (char*)d_ws;

  // ws: vv 8KB | score 1MB | fvT 51.4MB | fuH 51.4MB | fvH 51.4MB |
  //     vvpart 1.6MB | part (splitk * 2MB)
  const size_t HVF = (size_t)P_DIM * F_DIM * V_DIM * 2;   // 51,380,224
  float* vv = (float*)ws;
  unsigned short* score = (unsigned short*)(ws + 8192);
  unsigned short* fvT = (unsigned short*)(ws + 8192 + 1048576);
  unsigned short* fuH = (unsigned short*)(ws + 8192 + 1048576 + HVF);
  unsigned short* fvH = (unsigned short*)(ws + 8192 + 1048576 + 2 * HVF);
  size_t vvpartBase = 8192 + 1048576 + 3 * HVF;
  float* vvpart = (float*)(ws + vvpartBase);
  size_t partBase = vvpartBase + (size_t)(F_DIM / 64) * P_DIM * V_DIM * 4;
  float* part = (float*)(ws + partBase);

  const size_t puv4 = (size_t)P_DIM * U_DIM * V_DIM * 4;
  int splitk = 1;
  const int cands[5] = {14, 7, 4, 2, 1};     // all divide 196 -> chunk % 64 == 0
  for (int i = 0; i < 5; ++i) {
    if (partBase + (size_t)cands[i] * puv4 <= ws_size) { splitk = cands[i]; break; }
  }
  int chunk = F_DIM / splitk;

  int n4 = (P_DIM * U_DIM * F_DIM) / 4;
  copy_fu<<<2048, 256, 0, stream>>>(fu, out, (ushort4*)fuH, n4);
  prep_fv<<<dim3(F_DIM / 64, V_DIM / 64, P_DIM), 256, 0, stream>>>(fv, fvT, fvH,
                                                                   vvpart);
  vv_reduce<<<P_DIM * 4, 256, 0, stream>>>(vvpart, vv);
  uv_gemm<<<splitk * 32, 256, 0, stream>>>(fuH, fvH, part, splitk, chunk);
  reduce_softmax<<<P_DIM * U_DIM, 256, 0, stream>>>(part, vv, score, splitk);
  pv_gemm<<<dim3(2, F_DIM / 64, P_DIM), 256, 0, stream>>>(
      score, fvT, out + (size_t)P_DIM * U_DIM * F_DIM);
}